// Round 10
// baseline (317.174 us; speedup 1.0000x reference)
//
#include <hip/hip_runtime.h>

#define T       256
#define BSH     12
#define BS      4096            // nodes per col-bucket / rows per row-subbucket
#define MAXC    640             // max cells (25x25=625 for N=100000)
#define EPB     4096            // edges per count/scatter block
#define EPT     (EPB / T)       // 16 edges per thread

// ---------- count: per-block 625-bin histogram -> cell-major matrix ----------
// cntT[c * ebp + g] = #edges of block g in cell c
__global__ void k_count(const int* __restrict__ col, const int* __restrict__ row,
                        int* __restrict__ cntT, int E, int nbr, int ncell, int ebp) {
    __shared__ int hist[MAXC];
    int t = threadIdx.x, g = blockIdx.x;
    for (int j = t; j < ncell; j += T) hist[j] = 0;
    __syncthreads();
    int base = g * EPB;
    int hiE  = min(E, base + EPB);
    if (base + EPB <= E) {
        const int4* col4 = (const int4*)(col + base);
        const int4* row4 = (const int4*)(row + base);
#pragma unroll
        for (int k = 0; k < EPT / 4; ++k) {
            int4 c = col4[t + k * T];
            int4 r = row4[t + k * T];
            atomicAdd(&hist[(c.x >> BSH) * nbr + (r.x >> BSH)], 1);
            atomicAdd(&hist[(c.y >> BSH) * nbr + (r.y >> BSH)], 1);
            atomicAdd(&hist[(c.z >> BSH) * nbr + (r.z >> BSH)], 1);
            atomicAdd(&hist[(c.w >> BSH) * nbr + (r.w >> BSH)], 1);
        }
    } else {
        for (int e = base + t; e < hiE; e += T)
            atomicAdd(&hist[(col[e] >> BSH) * nbr + (row[e] >> BSH)], 1);
    }
    __syncthreads();
    for (int j = t; j < ncell; j += T) cntT[(size_t)j * ebp + g] = hist[j];
}

// ---------- scan: one block per cell, in-place exclusive scan over eb blocks ----------
__global__ void k_scan(int* __restrict__ cntT, int* __restrict__ tot, int eb, int ebp) {
    __shared__ int tsum[T];
    __shared__ int carry;
    int c = blockIdx.x, t = threadIdx.x;
    if (t == 0) carry = 0;
    __syncthreads();
    int rounds = (eb + T - 1) / T;
    for (int jr = 0; jr < rounds; ++jr) {
        int idx = jr * T + t;
        int v = (idx < eb) ? cntT[(size_t)c * ebp + idx] : 0;
        tsum[t] = v;
        __syncthreads();
        for (int d = 1; d < T; d <<= 1) {
            int o = (t >= d) ? tsum[t - d] : 0;
            __syncthreads();
            tsum[t] += o;
            __syncthreads();
        }
        int excl = tsum[t] - v + carry;
        if (idx < eb) cntT[(size_t)c * ebp + idx] = excl;   // in place
        __syncthreads();
        if (t == 0) carry += tsum[T - 1];
        __syncthreads();
    }
    if (t == 0) tot[c] = carry;
}

// ---------- scatter: 625-bin LDS bucket-sort of one 4096-edge tile ----------
// record.x = (col & 4095) << 17 | row (17 bits), record.y = bits(w)
__global__ void k_scatter(const int* __restrict__ row, const int* __restrict__ col,
                          const float* __restrict__ w,
                          const int* __restrict__ ofsT,   // scanned cntT
                          const int* __restrict__ tot,
                          int2* __restrict__ rec, int E, int nbr, int ncell, int ebp) {
    __shared__ int2 buf[EPB];            // 32 KB
    __shared__ unsigned short bkt[EPB];  // 8 KB
    __shared__ int hist[MAXC], rnk[MAXC], lofs[MAXC], rbase[MAXC];
    int t = threadIdx.x, g = blockIdx.x;
    for (int j = t; j < ncell; j += T) { hist[j] = 0; rnk[j] = 0; }
    __syncthreads();
    int base = g * EPB;
    int hiE  = min(E, base + EPB);
    bool full = (base + EPB <= E);

    // phase A: tile histogram
    if (full) {
        const int4* col4 = (const int4*)(col + base);
        const int4* row4 = (const int4*)(row + base);
#pragma unroll
        for (int k = 0; k < EPT / 4; ++k) {
            int4 c = col4[t + k * T];
            int4 r = row4[t + k * T];
            atomicAdd(&hist[(c.x >> BSH) * nbr + (r.x >> BSH)], 1);
            atomicAdd(&hist[(c.y >> BSH) * nbr + (r.y >> BSH)], 1);
            atomicAdd(&hist[(c.z >> BSH) * nbr + (r.z >> BSH)], 1);
            atomicAdd(&hist[(c.w >> BSH) * nbr + (r.w >> BSH)], 1);
        }
    } else {
        for (int e = base + t; e < hiE; e += T)
            atomicAdd(&hist[(col[e] >> BSH) * nbr + (row[e] >> BSH)], 1);
    }
    __syncthreads();

    // wave 0: dual scan — cell bases (padded tot) and tile-local offsets (hist)
    if (t < 64) {
        int carryA = 0, carryB = 0;
        for (int ch = 0; ch * 64 < ncell; ++ch) {
            int i = ch * 64 + t;
            int tv = (i < ncell) ? ((tot[i] + 7) & ~7) : 0;
            int hv = (i < ncell) ? hist[i] : 0;
            int ia = tv, ib = hv;
#pragma unroll
            for (int d = 1; d < 64; d <<= 1) {
                int oa = __shfl_up(ia, d, 64);
                int ob = __shfl_up(ib, d, 64);
                if (t >= d) { ia += oa; ib += ob; }
            }
            if (i < ncell) {
                lofs[i]  = ib - hv + carryB;
                rbase[i] = (ia - tv + carryA) + ofsT[(size_t)i * ebp + g];
            }
            carryA += __shfl(ia, 63, 64);
            carryB += __shfl(ib, 63, 64);
        }
    }
    __syncthreads();

    // phase B: re-read (L2-hot), rank, write bucket-sorted into LDS
    if (full) {
        const int4*   col4 = (const int4*)(col + base);
        const int4*   row4 = (const int4*)(row + base);
        const float4* w4   = (const float4*)(w + base);
#pragma unroll
        for (int k = 0; k < EPT / 4; ++k) {
            int4 c = col4[t + k * T];
            int4 r = row4[t + k * T];
            float4 wv = w4[t + k * T];
            int b, rk, pos;
            b = (c.x >> BSH) * nbr + (r.x >> BSH); rk = atomicAdd(&rnk[b], 1); pos = lofs[b] + rk;
            buf[pos] = make_int2(((c.x & (BS-1)) << 17) | r.x, __float_as_int(wv.x)); bkt[pos] = (unsigned short)b;
            b = (c.y >> BSH) * nbr + (r.y >> BSH); rk = atomicAdd(&rnk[b], 1); pos = lofs[b] + rk;
            buf[pos] = make_int2(((c.y & (BS-1)) << 17) | r.y, __float_as_int(wv.y)); bkt[pos] = (unsigned short)b;
            b = (c.z >> BSH) * nbr + (r.z >> BSH); rk = atomicAdd(&rnk[b], 1); pos = lofs[b] + rk;
            buf[pos] = make_int2(((c.z & (BS-1)) << 17) | r.z, __float_as_int(wv.z)); bkt[pos] = (unsigned short)b;
            b = (c.w >> BSH) * nbr + (r.w >> BSH); rk = atomicAdd(&rnk[b], 1); pos = lofs[b] + rk;
            buf[pos] = make_int2(((c.w & (BS-1)) << 17) | r.w, __float_as_int(wv.w)); bkt[pos] = (unsigned short)b;
        }
    } else {
        for (int e = base + t; e < hiE; e += T) {
            int cc = col[e], rr = row[e];
            int b = (cc >> BSH) * nbr + (rr >> BSH);
            int rk = atomicAdd(&rnk[b], 1);
            int pos = lofs[b] + rk;
            buf[pos] = make_int2(((cc & (BS-1)) << 17) | rr, __float_as_int(w[e]));
            bkt[pos] = (unsigned short)b;
        }
    }
    __syncthreads();

    // coalesced copy-out
    int totalT = hiE - base;
    for (int j = t; j < totalT; j += T) {
        int b = bkt[j];
        rec[rbase[b] + (j - lofs[b])] = buf[j];
    }
}

// ---------- accumulate: one block per cell; src gathers served from LDS ----------
template <bool HAS_SRC>
__global__ void k_acc(const int2* __restrict__ rec, const int* __restrict__ tot,
                      const float* __restrict__ src, float* __restrict__ part,
                      int N, int nbr, int ncell) {
    __shared__ float acc[BS];    // 16 KB
    __shared__ float srcl[BS];   // 16 KB
    __shared__ int sBase;
    int t = threadIdx.x, c = blockIdx.x;
    // cell base = prefix of padded tot over cells < c (wave 0)
    if (t < 64) {
        int s = 0;
        for (int ch = 0; ch * 64 < c; ++ch) {
            int i = ch * 64 + t;
            if (i < c) s += (tot[i] + 7) & ~7;
        }
#pragma unroll
        for (int d = 1; d < 64; d <<= 1) s += __shfl_xor(s, d, 64);
        if (t == 0) sBase = s;
    }
    for (int j = t; j < BS; j += T) acc[j] = 0.0f;
    if (HAS_SRC) {
        int rb = c % nbr;
        int base = rb << BSH;
        for (int j = t; j < BS; j += T) {
            int gg = base + j;
            srcl[j] = (gg < N) ? src[gg] : 0.0f;
        }
    }
    __syncthreads();
    int lo = sBase;
    int hi = lo + tot[c];
    const int4* rec4 = (const int4*)rec;
    int i = lo + t * 8;
    for (; i + 7 < hi; i += T * 8) {
        int4 q0 = rec4[(i >> 1) + 0];
        int4 q1 = rec4[(i >> 1) + 1];
        int4 q2 = rec4[(i >> 1) + 2];
        int4 q3 = rec4[(i >> 1) + 3];
        float v0 = __int_as_float(q0.y), v1 = __int_as_float(q0.w);
        float v2 = __int_as_float(q1.y), v3 = __int_as_float(q1.w);
        float v4 = __int_as_float(q2.y), v5 = __int_as_float(q2.w);
        float v6 = __int_as_float(q3.y), v7 = __int_as_float(q3.w);
        if (HAS_SRC) {
            v0 *= srcl[q0.x & (BS-1)]; v1 *= srcl[q0.z & (BS-1)];
            v2 *= srcl[q1.x & (BS-1)]; v3 *= srcl[q1.z & (BS-1)];
            v4 *= srcl[q2.x & (BS-1)]; v5 *= srcl[q2.z & (BS-1)];
            v6 *= srcl[q3.x & (BS-1)]; v7 *= srcl[q3.z & (BS-1)];
        }
        atomicAdd(&acc[((unsigned)q0.x) >> 17], v0);
        atomicAdd(&acc[((unsigned)q0.z) >> 17], v1);
        atomicAdd(&acc[((unsigned)q1.x) >> 17], v2);
        atomicAdd(&acc[((unsigned)q1.z) >> 17], v3);
        atomicAdd(&acc[((unsigned)q2.x) >> 17], v4);
        atomicAdd(&acc[((unsigned)q2.z) >> 17], v5);
        atomicAdd(&acc[((unsigned)q3.x) >> 17], v6);
        atomicAdd(&acc[((unsigned)q3.z) >> 17], v7);
    }
    for (; i < hi; ++i) {                        // tail owned by exactly one thread
        int2 r = rec[i];
        float v = __int_as_float(r.y);
        if (HAS_SRC) v *= srcl[r.x & (BS-1)];
        atomicAdd(&acc[((unsigned)r.x) >> 17], v);
    }
    __syncthreads();
    float* dst = part + (size_t)c * BS;
    for (int j = t; j < BS; j += T) dst[j] = acc[j];
}

// ---------- reduce + pointwise ----------
__device__ __forceinline__ float reduceM(const float* __restrict__ part, int n, int nbr) {
    int b = n >> BSH, o = n & (BS - 1);
    const float* pp = part + (size_t)b * nbr * BS + o;
    float s = 0.0f;
    for (int m = 0; m < nbr; ++m) s += pp[(size_t)m * BS];
    return s;
}

__global__ void k_red_dinv(const float* __restrict__ part, const float* __restrict__ x,
                           float* __restrict__ dinv, float* __restrict__ p, int N, int nbr) {
    int i = blockIdx.x * blockDim.x + threadIdx.x;
    if (i < N) {
        float d  = reduceM(part, i, nbr) + 1.0f;   // +1 = self-loop
        float di = rsqrtf(d);
        dinv[i] = di;
        p[i] = di * x[i];
    }
}

__global__ void k_red_mlp(const float* __restrict__ part, const float* __restrict__ dinv,
                          const float* __restrict__ p,
                          const float* __restrict__ W1, const float* __restrict__ b1,
                          const float* __restrict__ W2,
                          float* __restrict__ q, int N, int nbr) {
    int i = blockIdx.x * blockDim.x + threadIdx.x;
    if (i < N) {
        float di = dinv[i];
        float s  = di * reduceM(part, i, nbr) + di * p[i];
        float acc = 0.0f;
#pragma unroll
        for (int k = 0; k < 16; ++k) {
            float h = fmaxf(s * W1[k] + b1[k], 0.0f);
            acc += h * W2[k];
        }
        q[i] = di * acc;
    }
}

__global__ void k_red_out(const float* __restrict__ part, const float* __restrict__ dinv,
                          const float* __restrict__ q, const float* __restrict__ b2,
                          float* __restrict__ out, int N, int nbr) {
    int i = blockIdx.x * blockDim.x + threadIdx.x;
    if (i < N) {
        float di = dinv[i];
        out[i] = di * reduceM(part, i, nbr) + di * q[i] + b2[0];
    }
}

extern "C" void kernel_launch(void* const* d_in, const int* in_sizes, int n_in,
                              void* d_out, int out_size, void* d_ws, size_t ws_size,
                              hipStream_t stream) {
    const float* x  = (const float*)d_in[0];
    const int*   ei = (const int*)  d_in[1];
    const float* ew = (const float*)d_in[2];
    const float* W1 = (const float*)d_in[3];
    const float* b1 = (const float*)d_in[4];
    const float* W2 = (const float*)d_in[5];
    const float* b2 = (const float*)d_in[6];

    const int N = in_sizes[0];       // x is [N,1]
    const int E = in_sizes[2];       // edge_attr is [E]
    const int* row = ei;             // edge_index[0] = source
    const int* col = ei + E;         // edge_index[1] = target
    const int nbc   = (N + BS - 1) >> BSH;    // 25 col-buckets
    const int nbr   = nbc;                    // 25 row-subbuckets
    const int ncell = nbc * nbr;              // 625
    const int eb    = (E + EPB - 1) / EPB;    // 1221
    const int ebp   = (eb + 63) & ~63;        // 1248

    // workspace (~54.7 MB), 256 B aligned
    char* wsp = (char*)d_ws;
    auto take = [&](size_t bytes) {
        char* r = wsp; wsp += (bytes + 255) & ~(size_t)255; return (void*)r;
    };
    int2*  rec  = (int2*) take((size_t)(E + 8 * MAXC) * 8);     // 40.04 MB
    float* part = (float*)take((size_t)ncell * BS * 4);         // 10.24 MB
    int*   cntT = (int*)  take((size_t)ncell * ebp * 4);        // 3.12 MB (counts -> offsets in place)
    int*   tot  = (int*)  take(MAXC * 4);
    float* dinv = (float*)take((size_t)N * 4);
    float* p    = (float*)take((size_t)N * 4);
    float* q    = (float*)take((size_t)N * 4);

    float* out = (float*)d_out;

    const int nbk = (N + T - 1) / T;          // 391

    k_count  <<<eb, T, 0, stream>>>(col, row, cntT, E, nbr, ncell, ebp);
    k_scan   <<<ncell, T, 0, stream>>>(cntT, tot, eb, ebp);
    k_scatter<<<eb, T, 0, stream>>>(row, col, ew, cntT, tot, rec, E, nbr, ncell, ebp);

    // degree
    k_acc<false><<<ncell, T, 0, stream>>>(rec, tot, nullptr, part, N, nbr, ncell);
    k_red_dinv  <<<nbk, T, 0, stream>>>(part, x, dinv, p, N, nbr);

    // layer 1
    k_acc<true><<<ncell, T, 0, stream>>>(rec, tot, p, part, N, nbr, ncell);
    k_red_mlp  <<<nbk, T, 0, stream>>>(part, dinv, p, W1, b1, W2, q, N, nbr);

    // layer 2
    k_acc<true><<<ncell, T, 0, stream>>>(rec, tot, q, part, N, nbr, ncell);
    k_red_out  <<<nbk, T, 0, stream>>>(part, dinv, q, b2, out, N, nbr);
}

// Round 11
// 261.993 us; speedup vs baseline: 1.2106x; 1.2106x over previous
//
#include <hip/hip_runtime.h>

#define T       256
#define BSHIFT  12
#define BSIZE   4096            // nodes per bucket
#define MAXNB   32              // max buckets (N<=131072)
#define M       32              // accumulate slices per bucket
#define EPB     2048            // edges per count/scatter block
#define EPT     (EPB / T)       // 8 edges per thread

// ---------- count: per-block bucket histogram -> plain-store matrix ----------
// cntT[b * ebp + g] = #edges of block g in bucket b   (transposed for scan)
__global__ void k_count(const int* __restrict__ col, int* __restrict__ cntT,
                        int E, int nb, int ebp) {
    __shared__ int hist[MAXNB];
    int t = threadIdx.x, g = blockIdx.x;
    if (t < MAXNB) hist[t] = 0;
    __syncthreads();
    int base = g * EPB;
    bool full = (base + EPB <= E);
    if (full) {
#pragma unroll
        for (int k = 0; k < EPT / 4; ++k) {
            int4 c = *(const int4*)(col + base + (t + k * T) * 4);
            atomicAdd(&hist[c.x >> BSHIFT], 1);
            atomicAdd(&hist[c.y >> BSHIFT], 1);
            atomicAdd(&hist[c.z >> BSHIFT], 1);
            atomicAdd(&hist[c.w >> BSHIFT], 1);
        }
    } else {
        for (int k = 0; k < EPT; ++k) {
            int e = base + t + k * T;
            if (e < E) atomicAdd(&hist[col[e] >> BSHIFT], 1);
        }
    }
    __syncthreads();
    if (t < nb) cntT[t * ebp + g] = hist[t];
}

// ---------- scan: one block per bucket, exclusive scan over eb blocks ----------
__global__ void k_scan(const int* __restrict__ cntT, int* __restrict__ ofsT,
                       int* __restrict__ tot, int eb, int ebp) {
    __shared__ int tsum[T];
    __shared__ int carry;
    int b = blockIdx.x, t = threadIdx.x;
    if (t == 0) carry = 0;
    __syncthreads();
    int rounds = (eb + T - 1) / T;
    for (int jr = 0; jr < rounds; ++jr) {
        int idx = jr * T + t;
        int v = (idx < eb) ? cntT[b * ebp + idx] : 0;
        tsum[t] = v;
        __syncthreads();
        for (int d = 1; d < T; d <<= 1) {
            int o = (t >= d) ? tsum[t - d] : 0;
            __syncthreads();
            tsum[t] += o;
            __syncthreads();
        }
        int excl = tsum[t] - v + carry;
        if (idx < eb) ofsT[b * ebp + idx] = excl;
        __syncthreads();
        if (t == 0) carry += tsum[T - 1];
        __syncthreads();
    }
    if (t == 0) tot[b] = carry;
}

// ---------- scatter: LDS bucket-sort one 2048-edge tile, coalesced copy-out ----------
// record.x = (col & 4095) << 17 | row  (row < 2^17), record.y = bits(w)
// Bucket regions padded to x8 records; block 0 zero-fills the pad slots.
__global__ void k_scatter(const int* __restrict__ row, const int* __restrict__ col,
                          const float* __restrict__ w,
                          const int* __restrict__ cntT, const int* __restrict__ ofsT,
                          const int* __restrict__ tot,
                          int2* __restrict__ rec, int E, int nb, int ebp) {
    __shared__ int  lofs[MAXNB + 1];
    __shared__ int  rnk[MAXNB];
    __shared__ int  rbase[MAXNB];
    __shared__ int2 buf[EPB];          // 16 KB
    __shared__ unsigned char bkt[EPB]; // 2 KB
    int t = threadIdx.x, g = blockIdx.x;
    if (t < MAXNB) rnk[t] = 0;
    if (t < 64) {
        // scan padded tot (x8) -> bucket bases (exclusive), in-lane
        int tv = (t < nb) ? ((tot[t] + 7) & ~7) : 0;
        int incA = tv;
#pragma unroll
        for (int d = 1; d < 32; d <<= 1) {
            int o = __shfl_up(incA, d, 64);
            if (t >= d) incA += o;
        }
        // scan this block's count row -> tile-local offsets
        int h = (t < nb) ? cntT[t * ebp + g] : 0;
        int incB = h;
#pragma unroll
        for (int d = 1; d < 32; d <<= 1) {
            int o = __shfl_up(incB, d, 64);
            if (t >= d) incB += o;
        }
        if (t == 0) lofs[0] = 0;
        if (t < nb) {
            int bstart = incA - tv;
            lofs[t + 1] = incB;
            rbase[t] = bstart + ofsT[t * ebp + g];     // bucket base + my offset
            if (g == 0) {                              // zero the pad slots once
                int tb = tot[t];
                for (int j = tb; j < ((tb + 7) & ~7); ++j)
                    rec[bstart + j] = make_int2(0, 0); // x=0 -> acc[0] += 0.0f
            }
        }
    }
    __syncthreads();

    int base = g * EPB;
    bool full = (base + EPB <= E);
    if (full) {
#pragma unroll
        for (int k = 0; k < EPT / 4; ++k) {
            int idx = base + (t + k * T) * 4;
            int4   c  = *(const int4*)(col + idx);
            int4   r  = *(const int4*)(row + idx);
            float4 wv = *(const float4*)(w + idx);
            int b, rk, pos;
            b = c.x >> BSHIFT; rk = atomicAdd(&rnk[b], 1); pos = lofs[b] + rk;
            buf[pos] = make_int2(((c.x & (BSIZE-1)) << 17) | r.x, __float_as_int(wv.x));
            bkt[pos] = (unsigned char)b;
            b = c.y >> BSHIFT; rk = atomicAdd(&rnk[b], 1); pos = lofs[b] + rk;
            buf[pos] = make_int2(((c.y & (BSIZE-1)) << 17) | r.y, __float_as_int(wv.y));
            bkt[pos] = (unsigned char)b;
            b = c.z >> BSHIFT; rk = atomicAdd(&rnk[b], 1); pos = lofs[b] + rk;
            buf[pos] = make_int2(((c.z & (BSIZE-1)) << 17) | r.z, __float_as_int(wv.z));
            bkt[pos] = (unsigned char)b;
            b = c.w >> BSHIFT; rk = atomicAdd(&rnk[b], 1); pos = lofs[b] + rk;
            buf[pos] = make_int2(((c.w & (BSIZE-1)) << 17) | r.w, __float_as_int(wv.w));
            bkt[pos] = (unsigned char)b;
        }
    } else {
        for (int k = 0; k < EPT; ++k) {
            int e = base + t + k * T;
            if (e < E) {
                int c = col[e];
                int b = c >> BSHIFT;
                int rk = atomicAdd(&rnk[b], 1);
                int pos = lofs[b] + rk;
                buf[pos] = make_int2(((c & (BSIZE-1)) << 17) | row[e], __float_as_int(w[e]));
                bkt[pos] = (unsigned char)b;
            }
        }
    }
    __syncthreads();
    int total = lofs[nb];
    for (int j = t; j < total; j += T) {       // coalesced copy-out
        int b = bkt[j];
        rec[rbase[b] + (j - lofs[b])] = buf[j];
    }
}

// ---------- accumulate: LDS scatter-add of one bucket slice ----------
// Lane-contiguous record loads: each wave-load reads 1 KB contiguous (16 lines),
// not 64 scattered lines as with per-thread-blocked indexing.
template <bool HAS_SRC>
__global__ void k_acc(const int2* __restrict__ rec, const int* __restrict__ tot,
                      const float* __restrict__ src, float* __restrict__ part, int nb) {
    __shared__ float acc[BSIZE];
    __shared__ int   bst[MAXNB];
    int t = threadIdx.x, g = blockIdx.x;
    int b = g / M, m = g % M;
    if (t < 64) {                               // bucket bases from padded tot (x8)
        int tv = (t < nb) ? ((tot[t] + 7) & ~7) : 0;
        int inc = tv;
#pragma unroll
        for (int d = 1; d < 32; d <<= 1) {
            int o = __shfl_up(inc, d, 64);
            if (t >= d) inc += o;
        }
        if (t < nb) bst[t] = inc - tv;
    }
    for (int j = t; j < BSIZE; j += T) acc[j] = 0.0f;
    __syncthreads();
    int s   = bst[b];
    int tbp = (tot[b] + 7) & ~7;                // padded count (pads zeroed)
    int chunk = ((tbp + M - 1) / M + 7) & ~7;   // x8 records per slice
    int lo = s + m * chunk;
    int hi = min(s + tbp, lo + chunk);
    const int4* rec4 = (const int4*)rec;        // 2 records per int4
    int lo4 = lo >> 1, hi4 = hi >> 1;           // x4-int4 aligned
    for (int base = lo4 + t; base < hi4; base += 4 * T) {
        int4 q0 = make_int4(0,0,0,0), q1 = q0, q2 = q0, q3 = q0;
        q0 = rec4[base];
        if (base + 1*T < hi4) q1 = rec4[base + 1*T];
        if (base + 2*T < hi4) q2 = rec4[base + 2*T];
        if (base + 3*T < hi4) q3 = rec4[base + 3*T];
        float v0 = __int_as_float(q0.y), v1 = __int_as_float(q0.w);
        float v2 = __int_as_float(q1.y), v3 = __int_as_float(q1.w);
        float v4 = __int_as_float(q2.y), v5 = __int_as_float(q2.w);
        float v6 = __int_as_float(q3.y), v7 = __int_as_float(q3.w);
        if (HAS_SRC) {
            v0 *= src[q0.x & 0x1FFFF]; v1 *= src[q0.z & 0x1FFFF];
            v2 *= src[q1.x & 0x1FFFF]; v3 *= src[q1.z & 0x1FFFF];
            v4 *= src[q2.x & 0x1FFFF]; v5 *= src[q2.z & 0x1FFFF];
            v6 *= src[q3.x & 0x1FFFF]; v7 *= src[q3.z & 0x1FFFF];
        }
        atomicAdd(&acc[((unsigned)q0.x) >> 17], v0);
        atomicAdd(&acc[((unsigned)q0.z) >> 17], v1);
        atomicAdd(&acc[((unsigned)q1.x) >> 17], v2);
        atomicAdd(&acc[((unsigned)q1.z) >> 17], v3);
        atomicAdd(&acc[((unsigned)q2.x) >> 17], v4);
        atomicAdd(&acc[((unsigned)q2.z) >> 17], v5);
        atomicAdd(&acc[((unsigned)q3.x) >> 17], v6);
        atomicAdd(&acc[((unsigned)q3.z) >> 17], v7);
    }
    __syncthreads();
    float* dst = part + (size_t)g * BSIZE;
    for (int j = t; j < BSIZE; j += T) dst[j] = acc[j];
}

// ---------- reduce + pointwise ----------
__device__ __forceinline__ float reduceM(const float* __restrict__ part, int n) {
    int b = n >> BSHIFT, o = n & (BSIZE - 1);
    const float* pp = part + (size_t)b * M * BSIZE + o;
    float s = 0.0f;
#pragma unroll
    for (int m = 0; m < M; ++m) s += pp[(size_t)m * BSIZE];
    return s;
}

__global__ void k_red_dinv(const float* __restrict__ part, const float* __restrict__ x,
                           float* __restrict__ dinv, float* __restrict__ p, int N) {
    int i = blockIdx.x * blockDim.x + threadIdx.x;
    if (i < N) {
        float d  = reduceM(part, i) + 1.0f;     // +1 = self-loop
        float di = rsqrtf(d);
        dinv[i] = di;
        p[i] = di * x[i];
    }
}

__global__ void k_red_mlp(const float* __restrict__ part, const float* __restrict__ dinv,
                          const float* __restrict__ p,
                          const float* __restrict__ W1, const float* __restrict__ b1,
                          const float* __restrict__ W2,
                          float* __restrict__ q, int N) {
    int i = blockIdx.x * blockDim.x + threadIdx.x;
    if (i < N) {
        float di = dinv[i];
        float s  = di * reduceM(part, i) + di * p[i];
        float acc = 0.0f;
#pragma unroll
        for (int k = 0; k < 16; ++k) {
            float h = fmaxf(s * W1[k] + b1[k], 0.0f);
            acc += h * W2[k];
        }
        q[i] = di * acc;
    }
}

__global__ void k_red_out(const float* __restrict__ part, const float* __restrict__ dinv,
                          const float* __restrict__ q, const float* __restrict__ b2,
                          float* __restrict__ out, int N) {
    int i = blockIdx.x * blockDim.x + threadIdx.x;
    if (i < N) {
        float di = dinv[i];
        out[i] = di * reduceM(part, i) + di * q[i] + b2[0];
    }
}

extern "C" void kernel_launch(void* const* d_in, const int* in_sizes, int n_in,
                              void* d_out, int out_size, void* d_ws, size_t ws_size,
                              hipStream_t stream) {
    const float* x  = (const float*)d_in[0];
    const int*   ei = (const int*)  d_in[1];
    const float* ew = (const float*)d_in[2];
    const float* W1 = (const float*)d_in[3];
    const float* b1 = (const float*)d_in[4];
    const float* W2 = (const float*)d_in[5];
    const float* b2 = (const float*)d_in[6];

    const int N = in_sizes[0];       // x is [N,1]
    const int E = in_sizes[2];       // edge_attr is [E]
    const int* row = ei;             // edge_index[0] = source
    const int* col = ei + E;         // edge_index[1] = target
    const int nb  = (N + BSIZE - 1) >> BSHIFT;   // 25
    const int eb  = (E + EPB - 1) / EPB;         // 2442
    const int ebp = (eb + 63) & ~63;             // padded row length

    // workspace layout (~55.1 MB), 256 B aligned
    char* wsp = (char*)d_ws;
    auto take = [&](size_t bytes) {
        char* r = wsp; wsp += (bytes + 255) & ~(size_t)255; return (void*)r;
    };
    int2*  rec  = (int2*) take((size_t)(E + 8 * MAXNB) * 8);   // 40.07 MB
    float* part = (float*)take((size_t)nb * M * BSIZE * 4);    // 13.11 MB
    float* dinv = (float*)take((size_t)N * 4);
    float* p    = (float*)take((size_t)N * 4);
    float* q    = (float*)take((size_t)N * 4);
    int*   cntT = (int*)  take((size_t)MAXNB * ebp * 4);       // 0.32 MB
    int*   ofsT = (int*)  take((size_t)MAXNB * ebp * 4);       // 0.32 MB
    int*   tot  = (int*)  take(MAXNB * 4);

    float* out = (float*)d_out;

    const int nbk = (N + T - 1) / T;
    const int ab  = nb * M;                      // 800

    k_count  <<<eb, T, 0, stream>>>(col, cntT, E, nb, ebp);
    k_scan   <<<nb, T, 0, stream>>>(cntT, ofsT, tot, eb, ebp);
    k_scatter<<<eb, T, 0, stream>>>(row, col, ew, cntT, ofsT, tot, rec, E, nb, ebp);

    // degree
    k_acc<false><<<ab, T, 0, stream>>>(rec, tot, nullptr, part, nb);
    k_red_dinv  <<<nbk, T, 0, stream>>>(part, x, dinv, p, N);

    // layer 1
    k_acc<true><<<ab, T, 0, stream>>>(rec, tot, p, part, nb);
    k_red_mlp  <<<nbk, T, 0, stream>>>(part, dinv, p, W1, b1, W2, q, N);

    // layer 2
    k_acc<true><<<ab, T, 0, stream>>>(rec, tot, q, part, nb);
    k_red_out  <<<nbk, T, 0, stream>>>(part, dinv, q, b2, out, N);
}

// Round 12
// 238.919 us; speedup vs baseline: 1.3275x; 1.0966x over previous
//
#include <hip/hip_runtime.h>

#define T       256
#define BSHIFT  12
#define BSIZE   4096            // nodes per bucket
#define MAXNB   32              // max buckets (N<=131072)
#define M       32              // accumulate slices per bucket
#define EPB     4096            // edges per count/scatter block
#define EPT     (EPB / T)       // 16 edges per thread

// ---------- count: per-block bucket histogram -> plain-store matrix ----------
// cntT[b * ebp + g] = #edges of block g in bucket b   (transposed for scan)
__global__ void k_count(const int* __restrict__ col, int* __restrict__ cntT,
                        int E, int nb, int ebp) {
    __shared__ int hist[MAXNB];
    int t = threadIdx.x, g = blockIdx.x;
    if (t < MAXNB) hist[t] = 0;
    __syncthreads();
    int base = g * EPB;
    bool full = (base + EPB <= E);
    if (full) {
#pragma unroll
        for (int k = 0; k < EPT / 4; ++k) {
            int4 c = *(const int4*)(col + base + (t + k * T) * 4);
            atomicAdd(&hist[c.x >> BSHIFT], 1);
            atomicAdd(&hist[c.y >> BSHIFT], 1);
            atomicAdd(&hist[c.z >> BSHIFT], 1);
            atomicAdd(&hist[c.w >> BSHIFT], 1);
        }
    } else {
        for (int k = 0; k < EPT; ++k) {
            int e = base + t + k * T;
            if (e < E) atomicAdd(&hist[col[e] >> BSHIFT], 1);
        }
    }
    __syncthreads();
    if (t < nb) cntT[t * ebp + g] = hist[t];
}

// ---------- scan: one block per bucket, exclusive scan over eb blocks ----------
__global__ void k_scan(const int* __restrict__ cntT, int* __restrict__ ofsT,
                       int* __restrict__ tot, int eb, int ebp) {
    __shared__ int tsum[T];
    __shared__ int carry;
    int b = blockIdx.x, t = threadIdx.x;
    if (t == 0) carry = 0;
    __syncthreads();
    int rounds = (eb + T - 1) / T;
    for (int jr = 0; jr < rounds; ++jr) {
        int idx = jr * T + t;
        int v = (idx < eb) ? cntT[b * ebp + idx] : 0;
        tsum[t] = v;
        __syncthreads();
        for (int d = 1; d < T; d <<= 1) {
            int o = (t >= d) ? tsum[t - d] : 0;
            __syncthreads();
            tsum[t] += o;
            __syncthreads();
        }
        int excl = tsum[t] - v + carry;
        if (idx < eb) ofsT[b * ebp + idx] = excl;
        __syncthreads();
        if (t == 0) carry += tsum[T - 1];
        __syncthreads();
    }
    if (t == 0) tot[b] = carry;
}

// ---------- scatter: LDS bucket-sort one 4096-edge tile, coalesced copy-out ----------
// record.x = (col & 4095) << 17 | row  (row < 2^17), record.y = bits(w)
__global__ void k_scatter(const int* __restrict__ row, const int* __restrict__ col,
                          const float* __restrict__ w,
                          const int* __restrict__ cntT, const int* __restrict__ ofsT,
                          const int* __restrict__ tot,
                          int2* __restrict__ rec, int E, int nb, int ebp) {
    __shared__ int  lofs[MAXNB + 1];
    __shared__ int  rnk[MAXNB];
    __shared__ int  rbase[MAXNB];
    __shared__ int2 buf[EPB];          // 32 KB
    __shared__ unsigned char bkt[EPB]; // 4 KB
    int t = threadIdx.x, g = blockIdx.x;
    if (t < MAXNB) rnk[t] = 0;
    if (t < 64) {
        // scan padded tot (x4) -> bucket bases (exclusive), in-lane
        int tv = (t < nb) ? ((tot[t] + 3) & ~3) : 0;
        int incA = tv;
#pragma unroll
        for (int d = 1; d < 32; d <<= 1) {
            int o = __shfl_up(incA, d, 64);
            if (t >= d) incA += o;
        }
        // scan this block's count row -> tile-local offsets
        int h = (t < nb) ? cntT[t * ebp + g] : 0;
        int incB = h;
#pragma unroll
        for (int d = 1; d < 32; d <<= 1) {
            int o = __shfl_up(incB, d, 64);
            if (t >= d) incB += o;
        }
        if (t == 0) lofs[0] = 0;
        if (t < nb) {
            lofs[t + 1] = incB;
            rbase[t] = (incA - tv) + ofsT[t * ebp + g];   // bucket base + my offset
        }
    }
    __syncthreads();

    int base = g * EPB;
    bool full = (base + EPB <= E);
    if (full) {
#pragma unroll
        for (int k = 0; k < EPT / 4; ++k) {
            int idx = base + (t + k * T) * 4;
            int4   c  = *(const int4*)(col + idx);
            int4   r  = *(const int4*)(row + idx);
            float4 wv = *(const float4*)(w + idx);
            int b, rk, pos;
            b = c.x >> BSHIFT; rk = atomicAdd(&rnk[b], 1); pos = lofs[b] + rk;
            buf[pos] = make_int2(((c.x & (BSIZE-1)) << 17) | r.x, __float_as_int(wv.x));
            bkt[pos] = (unsigned char)b;
            b = c.y >> BSHIFT; rk = atomicAdd(&rnk[b], 1); pos = lofs[b] + rk;
            buf[pos] = make_int2(((c.y & (BSIZE-1)) << 17) | r.y, __float_as_int(wv.y));
            bkt[pos] = (unsigned char)b;
            b = c.z >> BSHIFT; rk = atomicAdd(&rnk[b], 1); pos = lofs[b] + rk;
            buf[pos] = make_int2(((c.z & (BSIZE-1)) << 17) | r.z, __float_as_int(wv.z));
            bkt[pos] = (unsigned char)b;
            b = c.w >> BSHIFT; rk = atomicAdd(&rnk[b], 1); pos = lofs[b] + rk;
            buf[pos] = make_int2(((c.w & (BSIZE-1)) << 17) | r.w, __float_as_int(wv.w));
            bkt[pos] = (unsigned char)b;
        }
    } else {
        for (int k = 0; k < EPT; ++k) {
            int e = base + t + k * T;
            if (e < E) {
                int c = col[e];
                int b = c >> BSHIFT;
                int rk = atomicAdd(&rnk[b], 1);
                int pos = lofs[b] + rk;
                buf[pos] = make_int2(((c & (BSIZE-1)) << 17) | row[e], __float_as_int(w[e]));
                bkt[pos] = (unsigned char)b;
            }
        }
    }
    __syncthreads();
    int total = lofs[nb];
    for (int j = t; j < total; j += T) {       // coalesced copy-out
        int b = bkt[j];
        rec[rbase[b] + (j - lofs[b])] = buf[j];
    }
}

// ---------- accumulate: LDS scatter-add of one bucket slice (R9 form) ----------
template <bool HAS_SRC>
__global__ void k_acc(const int2* __restrict__ rec, const int* __restrict__ tot,
                      const float* __restrict__ src, float* __restrict__ part, int nb) {
    __shared__ float acc[BSIZE];
    __shared__ int   bst[MAXNB];
    int t = threadIdx.x, g = blockIdx.x;
    int b = g / M, m = g % M;
    if (t < 64) {                               // bucket bases from padded tot
        int tv = (t < nb) ? ((tot[t] + 3) & ~3) : 0;
        int inc = tv;
#pragma unroll
        for (int d = 1; d < 32; d <<= 1) {
            int o = __shfl_up(inc, d, 64);
            if (t >= d) inc += o;
        }
        if (t < nb) bst[t] = inc - tv;
    }
    for (int j = t; j < BSIZE; j += T) acc[j] = 0.0f;
    __syncthreads();
    int s  = bst[b];
    int tb = tot[b];
    int chunk = ((tb + M - 1) / M + 7) & ~7;    // x8 records per slice
    int lo = s + m * chunk;
    int hi = min(s + tb, lo + chunk);
    const int4* rec4 = (const int4*)rec;
    int i = lo + t * 8;
    for (; i + 7 < hi; i += T * 8) {
        int4 q0 = rec4[(i >> 1) + 0];
        int4 q1 = rec4[(i >> 1) + 1];
        int4 q2 = rec4[(i >> 1) + 2];
        int4 q3 = rec4[(i >> 1) + 3];
        float v0 = __int_as_float(q0.y), v1 = __int_as_float(q0.w);
        float v2 = __int_as_float(q1.y), v3 = __int_as_float(q1.w);
        float v4 = __int_as_float(q2.y), v5 = __int_as_float(q2.w);
        float v6 = __int_as_float(q3.y), v7 = __int_as_float(q3.w);
        if (HAS_SRC) {
            v0 *= src[q0.x & 0x1FFFF]; v1 *= src[q0.z & 0x1FFFF];
            v2 *= src[q1.x & 0x1FFFF]; v3 *= src[q1.z & 0x1FFFF];
            v4 *= src[q2.x & 0x1FFFF]; v5 *= src[q2.z & 0x1FFFF];
            v6 *= src[q3.x & 0x1FFFF]; v7 *= src[q3.z & 0x1FFFF];
        }
        atomicAdd(&acc[((unsigned)q0.x) >> 17], v0);
        atomicAdd(&acc[((unsigned)q0.z) >> 17], v1);
        atomicAdd(&acc[((unsigned)q1.x) >> 17], v2);
        atomicAdd(&acc[((unsigned)q1.z) >> 17], v3);
        atomicAdd(&acc[((unsigned)q2.x) >> 17], v4);
        atomicAdd(&acc[((unsigned)q2.z) >> 17], v5);
        atomicAdd(&acc[((unsigned)q3.x) >> 17], v6);
        atomicAdd(&acc[((unsigned)q3.z) >> 17], v7);
    }
    for (; i < hi; ++i) {                       // tail owned by exactly one thread
        int2 r = rec[i];
        float v = __int_as_float(r.y);
        if (HAS_SRC) v *= src[r.x & 0x1FFFF];
        atomicAdd(&acc[((unsigned)r.x) >> 17], v);
    }
    __syncthreads();
    float* dst = part + (size_t)g * BSIZE;
    for (int j = t; j < BSIZE; j += T) dst[j] = acc[j];
}

// ---------- reduce + pointwise ----------
__device__ __forceinline__ float reduceM(const float* __restrict__ part, int n) {
    int b = n >> BSHIFT, o = n & (BSIZE - 1);
    const float* pp = part + (size_t)b * M * BSIZE + o;
    float s = 0.0f;
#pragma unroll
    for (int m = 0; m < M; ++m) s += pp[(size_t)m * BSIZE];
    return s;
}

__global__ void k_red_dinv(const float* __restrict__ part, const float* __restrict__ x,
                           float* __restrict__ dinv, float* __restrict__ p, int N) {
    int i = blockIdx.x * blockDim.x + threadIdx.x;
    if (i < N) {
        float d  = reduceM(part, i) + 1.0f;     // +1 = self-loop
        float di = rsqrtf(d);
        dinv[i] = di;
        p[i] = di * x[i];
    }
}

__global__ void k_red_mlp(const float* __restrict__ part, const float* __restrict__ dinv,
                          const float* __restrict__ p,
                          const float* __restrict__ W1, const float* __restrict__ b1,
                          const float* __restrict__ W2,
                          float* __restrict__ q, int N) {
    int i = blockIdx.x * blockDim.x + threadIdx.x;
    if (i < N) {
        float di = dinv[i];
        float s  = di * reduceM(part, i) + di * p[i];
        float acc = 0.0f;
#pragma unroll
        for (int k = 0; k < 16; ++k) {
            float h = fmaxf(s * W1[k] + b1[k], 0.0f);
            acc += h * W2[k];
        }
        q[i] = di * acc;
    }
}

__global__ void k_red_out(const float* __restrict__ part, const float* __restrict__ dinv,
                          const float* __restrict__ q, const float* __restrict__ b2,
                          float* __restrict__ out, int N) {
    int i = blockIdx.x * blockDim.x + threadIdx.x;
    if (i < N) {
        float di = dinv[i];
        out[i] = di * reduceM(part, i) + di * q[i] + b2[0];
    }
}

extern "C" void kernel_launch(void* const* d_in, const int* in_sizes, int n_in,
                              void* d_out, int out_size, void* d_ws, size_t ws_size,
                              hipStream_t stream) {
    const float* x  = (const float*)d_in[0];
    const int*   ei = (const int*)  d_in[1];
    const float* ew = (const float*)d_in[2];
    const float* W1 = (const float*)d_in[3];
    const float* b1 = (const float*)d_in[4];
    const float* W2 = (const float*)d_in[5];
    const float* b2 = (const float*)d_in[6];

    const int N = in_sizes[0];       // x is [N,1]
    const int E = in_sizes[2];       // edge_attr is [E]
    const int* row = ei;             // edge_index[0] = source
    const int* col = ei + E;         // edge_index[1] = target
    const int nb  = (N + BSIZE - 1) >> BSHIFT;   // 25
    const int eb  = (E + EPB - 1) / EPB;         // 1221
    const int ebp = (eb + 63) & ~63;             // padded row length

    // workspace layout (~54.8 MB), 256 B aligned
    char* wsp = (char*)d_ws;
    auto take = [&](size_t bytes) {
        char* r = wsp; wsp += (bytes + 255) & ~(size_t)255; return (void*)r;
    };
    int2*  rec  = (int2*) take((size_t)(E + 4 * MAXNB) * 8);   // 40.07 MB
    float* part = (float*)take((size_t)nb * M * BSIZE * 4);    // 13.11 MB
    float* dinv = (float*)take((size_t)N * 4);
    float* p    = (float*)take((size_t)N * 4);
    float* q    = (float*)take((size_t)N * 4);
    int*   cntT = (int*)  take((size_t)MAXNB * ebp * 4);       // 0.16 MB
    int*   ofsT = (int*)  take((size_t)MAXNB * ebp * 4);       // 0.16 MB
    int*   tot  = (int*)  take(MAXNB * 4);

    float* out = (float*)d_out;

    const int nbk = (N + T - 1) / T;
    const int ab  = nb * M;                      // 800

    k_count  <<<eb, T, 0, stream>>>(col, cntT, E, nb, ebp);
    k_scan   <<<nb, T, 0, stream>>>(cntT, ofsT, tot, eb, ebp);
    k_scatter<<<eb, T, 0, stream>>>(row, col, ew, cntT, ofsT, tot, rec, E, nb, ebp);

    // degree
    k_acc<false><<<ab, T, 0, stream>>>(rec, tot, nullptr, part, nb);
    k_red_dinv  <<<nbk, T, 0, stream>>>(part, x, dinv, p, N);

    // layer 1
    k_acc<true><<<ab, T, 0, stream>>>(rec, tot, p, part, nb);
    k_red_mlp  <<<nbk, T, 0, stream>>>(part, dinv, p, W1, b1, W2, q, N);

    // layer 2
    k_acc<true><<<ab, T, 0, stream>>>(rec, tot, q, part, nb);
    k_red_out  <<<nbk, T, 0, stream>>>(part, dinv, q, b2, out, N);
}